// Round 2
// baseline (249.786 us; speedup 1.0000x reference)
//
#include <hip/hip_runtime.h>
#include <stdint.h>

typedef unsigned short u16;
typedef short s16x8 __attribute__((ext_vector_type(8)));
typedef float f32x4 __attribute__((ext_vector_type(4)));

#define SQ 2048
#define DH 64
#define BM 64
#define BN 64
#define STR 72             // prep-only LDS transpose stride (shorts)
#define SPECIAL_START 2040
#define NBH 32             // b*h
#define NKV 8              // b*hk
#define NQT 32
#define NITEMS (NBH * NQT) // 1024 work items (bh, qt)
#define ATTN_GRID 896      // < NITEMS so the queue can rebalance
// softclamp+softmax folded to exp2: p = 2^( t*poly(t*t) - KEF ), t = s * K1F
#define K1F  0.18033688011112043f    // 0.125 * log2(e)
#define KPAF 4.9244826e-9f           // (2/15)*k^2, k = (0.02/log2e)^2
#define KPBF -6.406040185576019e-5f  // -k/3
#define KEF  36.067376022224085f     // 25 * log2(e)  (constant softmax shift = 25)

union U8 { s16x8 v; short e[8]; };
union F4 { f32x4 v; float e[4]; };

__device__ __forceinline__ u16 f2bf(float x) {  // round-to-nearest-even
    uint32_t u = __float_as_uint(x);
    return (u16)((u + 0x7fffu + ((u >> 16) & 1u)) >> 16);
}
__device__ __forceinline__ uint32_t pkbf(float a, float b) {  // pack 2 bf16, 1 instr
    uint32_t r;
    asm("v_cvt_pk_bf16_f32 %0, %1, %2" : "=v"(r) : "v"(a), "v"(b));
    return r;
}
__device__ __forceinline__ float exp2hw(float x) {
    float r; asm("v_exp_f32 %0, %1" : "=v"(r) : "v"(x)); return r;
}
__device__ __forceinline__ float2 fsincos(float ang) {  // {sin, cos}, fast HW path
    float r = ang * 0.15915494309189535f;   // radians -> revolutions
    r -= floorf(r);
    float s, c;
    asm("v_sin_f32 %0, %1" : "=v"(s) : "v"(r));
    asm("v_cos_f32 %0, %1" : "=v"(c) : "v"(r));
    return make_float2(s, c);
}

// ---- prep: V tiles (transpose to [tile][d][kv]) + K rope rows (bf16) ----
// Q is NOT prestaged: each Q row is consumed exactly once -> roped inline in attn.
#define VTILES (NKV * 32)                 // 256 tile-blocks
#define RK (NKV * SQ)                     // 16384 K rows
#define KBLK (RK / 32)                    // 512 row-blocks (32 rows each)
__global__ __launch_bounds__(256)
void prep_kernel(const float* __restrict__ kg, const float* __restrict__ vg,
                 const float* __restrict__ rotg,
                 u16* __restrict__ kp, u16* __restrict__ vp,
                 uint32_t* __restrict__ cnt)
{
    const int tid = threadIdx.x;
    if (blockIdx.x == 0 && tid == 0) *cnt = 0u;
    if (blockIdx.x < VTILES) {
        // --- V: one 64x64 tile, transpose through LDS; vp[tile][d][kv] = V[kv][d] ---
        __shared__ short Vls[64 * STR];
        const int tile = blockIdx.x;                   // bkv*32 + kt
        const float* src = vg + ((size_t)(tile >> 5) * SQ + (size_t)(tile & 31) * 64) * DH;
        {
            int kv = tid >> 2, c0 = (tid & 3) * 16;
            const float* s4 = src + (size_t)kv * DH + c0;
            float4 f0 = *(const float4*)(s4);
            float4 f1 = *(const float4*)(s4 + 4);
            float4 f2 = *(const float4*)(s4 + 8);
            float4 f3 = *(const float4*)(s4 + 12);
            uint4 w0 = make_uint4(pkbf(f0.x, f0.y), pkbf(f0.z, f0.w),
                                  pkbf(f1.x, f1.y), pkbf(f1.z, f1.w));
            uint4 w1 = make_uint4(pkbf(f2.x, f2.y), pkbf(f2.z, f2.w),
                                  pkbf(f3.x, f3.y), pkbf(f3.z, f3.w));
            *(uint4*)&Vls[kv * STR + c0]     = w0;
            *(uint4*)&Vls[kv * STR + c0 + 8] = w1;
        }
        __syncthreads();
        {
            int d = tid >> 2, c0 = (tid & 3) * 16;
            U8 o0, o1;
#pragma unroll
            for (int j = 0; j < 16; j++)
                (j < 8 ? o0 : o1).e[j & 7] = Vls[(c0 + j) * STR + d];  // transpose
            u16* dst = vp + (((size_t)tile * 64 + d) << 6) + c0;
            *(s16x8*)dst       = o0.v;
            *(s16x8*)(dst + 8) = o1.v;
        }
    } else {
        // --- K rope: 32 rows per block, 8 elems per thread; HW sin/cos ---
        int bx = blockIdx.x - VTILES;
        int r8 = tid >> 3, c0 = (tid & 7) * 4;      // c0 in 0..28 (<32)
        int r = bx * 32 + r8;                        // r in [0, RK)
        const int s = r & (SQ - 1);
        const float* src = kg + (size_t)r * DH;
        u16*         dst = kp + (size_t)r * DH;
        float4 a  = *(const float4*)(src + c0);
        float4 b  = *(const float4*)(src + c0 + 32);
        float4 rv = *(const float4*)(rotg + (size_t)s * DH + c0);
        float2 s0 = fsincos(rv.x), s1 = fsincos(rv.y),
               s2 = fsincos(rv.z), s3 = fsincos(rv.w);
        float lo0 = a.x * s0.y - b.x * s0.x, hi0 = b.x * s0.y + a.x * s0.x;
        float lo1 = a.y * s1.y - b.y * s1.x, hi1 = b.y * s1.y + a.y * s1.x;
        float lo2 = a.z * s2.y - b.z * s2.x, hi2 = b.z * s2.y + a.z * s2.x;
        float lo3 = a.w * s3.y - b.w * s3.x, hi3 = b.w * s3.y + a.w * s3.x;
        *(uint2*)(dst + c0)      = make_uint2(pkbf(lo0, lo1), pkbf(lo2, lo3));
        *(uint2*)(dst + c0 + 32) = make_uint2(pkbf(hi0, hi1), pkbf(hi2, hi3));
    }
}

// ---- fast attn: NO K/V LDS. kf/vf fragments read directly from L2-resident
// kp/vp as aligned 16B/lane global loads. LDS = 8KB (Q stage + wave-private P
// round-trip). Zero barriers per ktile; 2 barriers per item (queue pop).
// S^T = K.Q^T via mfma(A=K,B=Q)   -> C: col(l15)=q, row(quad*4+c)=kv
// O^T = V^T.P via mfma(A=Vt,B=P)  -> C: col(l15)=q, row(quad*4+c)=d
__global__ __launch_bounds__(256, 6)
void attn_fast(const float* __restrict__ qg, const float* __restrict__ rotg,
               const u16* __restrict__ kp, const u16* __restrict__ vp,
               uint32_t* __restrict__ cnt, float* __restrict__ outg)
{
    const int tid = threadIdx.x;
    const int wv = tid >> 6, lane = tid & 63;
    const int l15 = lane & 15, quad = lane >> 4;
    const int swl = (l15 & 7) << 3;   // row-XOR swizzle (shorts)

    __shared__ __align__(16) short QPs[BM * 64];   // Q tile, then P rows (wave-private)
    __shared__ int s_w;

    for (;;) {
        __syncthreads();                       // QPs reuse + s_w protection
        if (tid == 0) s_w = (int)atomicAdd(cnt, 1u);
        __syncthreads();
        const int w = s_w;
        if (w >= NITEMS) break;
        // heavy-first; consecutive pops share bkv for L2 locality
        const int qt = (NQT - 1) - (w >> 5);
        const int u  = w & 31, bkv = u >> 2;
        const int bh = ((bkv >> 2) << 4) | ((bkv & 3) << 2) | (u & 3);
        const int qs = qt * BM;
        const int nkt = (qt / 4 + 1) * 4;      // block-causal: tiles fully allowed
        const int qglob = qs + wv * 16 + l15;

        // ---- stage Q with inline rope (wave-local rows: no barrier needed) ----
        {
            const int rr = tid >> 2, c0 = (tid & 3) * 8;   // rr = wv*16 + 0..15
            const int srow = qs + rr;
            const float* gq = qg + ((size_t)bh * SQ + srow) * DH;
            float a[8], b[8];
            *(float4*)&a[0] = *(const float4*)(gq + c0);
            *(float4*)&a[4] = *(const float4*)(gq + c0 + 4);
            *(float4*)&b[0] = *(const float4*)(gq + c0 + 32);
            *(float4*)&b[4] = *(const float4*)(gq + c0 + 36);
            const float* rrow = rotg + (size_t)srow * DH + c0;   // c0 < 32
            float lo[8], hi[8];
#pragma unroll
            for (int j = 0; j < 8; j++) {
                float2 sc = fsincos(rrow[j]);
                lo[j] = a[j] * sc.y - b[j] * sc.x;
                hi[j] = b[j] * sc.y + a[j] * sc.x;
            }
            const int sw2 = (rr & 7) << 3;
            uint4 w0 = make_uint4(pkbf(lo[0], lo[1]), pkbf(lo[2], lo[3]),
                                  pkbf(lo[4], lo[5]), pkbf(lo[6], lo[7]));
            uint4 w1 = make_uint4(pkbf(hi[0], hi[1]), pkbf(hi[2], hi[3]),
                                  pkbf(hi[4], hi[5]), pkbf(hi[6], hi[7]));
            *(uint4*)&QPs[rr * 64 + (c0 ^ sw2)]          = w0;
            *(uint4*)&QPs[rr * 64 + ((c0 + 32) ^ sw2)]   = w1;
        }

        // ---- preload Q fragments: B[n=q(l15)][k=quad*8+j] ----
        s16x8 qf[2];
#pragma unroll
        for (int ks = 0; ks < 2; ks++)
            qf[ks] = *(const s16x8*)&QPs[(wv * 16 + l15) * 64 + ((ks * 32 + quad * 8) ^ swl)];

        F4 oa[4];
#pragma unroll
        for (int mb = 0; mb < 4; mb++) oa[mb].v = (f32x4){0.f, 0.f, 0.f, 0.f};
        float lsum = 0.f;

        // per-lane fragment base: row = (kt*64 + mb*16 + l15), col = ks*32 + quad*8
        const u16* kbl = kp + (size_t)bkv * (SQ * DH) + l15 * 64 + quad * 8;
        const u16* vbl = vp + (size_t)bkv * (32 * 64 * 64) + l15 * 64 + quad * 8;
        short* prow = &QPs[(wv * 16 + l15) * 64];

#pragma unroll 2
        for (int kt = 0; kt < nkt; kt++) {
            const u16* kt_k = kbl + (size_t)kt * 4096;
            const u16* kt_v = vbl + (size_t)kt * 4096;

            // ---- QK^T: S^T[kv][q], fragments straight from L2 ----
            F4 sa[4];
            __builtin_amdgcn_s_setprio(1);
#pragma unroll
            for (int ks = 0; ks < 2; ks++)
#pragma unroll
                for (int mb = 0; mb < 4; mb++) {
                    s16x8 kf = *(const s16x8*)(kt_k + mb * 1024 + ks * 32);
                    sa[mb].v = __builtin_amdgcn_mfma_f32_16x16x32_bf16(
                        kf, qf[ks], ks ? sa[mb].v : (f32x4){0.f, 0.f, 0.f, 0.f}, 0, 0, 0);
                }
            __builtin_amdgcn_s_setprio(0);

            // ---- softclamp + constant-shift softmax (exp2-folded) ----
            F4 pa[4];
#pragma unroll
            for (int mb = 0; mb < 4; mb++)
#pragma unroll
                for (int c = 0; c < 4; c++) {
                    float t  = sa[mb].e[c] * K1F;
                    float w2 = t * t;
                    float poly = fmaf(w2, fmaf(w2, KPAF, KPBF), 1.0f);
                    pa[mb].e[c] = exp2hw(fmaf(t, poly, -KEF));
                }
            if (kt == 31 && qglob < SPECIAL_START) {   // special-token mask
#pragma unroll
                for (int mb = 0; mb < 4; mb++)
#pragma unroll
                    for (int c = 0; c < 4; c++) {
                        int kvglob = kt * BN + mb * 16 + quad * 4 + c;
                        if (kvglob >= SPECIAL_START) pa[mb].e[c] = 0.f;
                    }
            }
#pragma unroll
            for (int mb = 0; mb < 4; mb++) {
                lsum += (pa[mb].e[0] + pa[mb].e[1]) + (pa[mb].e[2] + pa[mb].e[3]);
                uint2 pw = make_uint2(pkbf(pa[mb].e[0], pa[mb].e[1]),
                                      pkbf(pa[mb].e[2], pa[mb].e[3]));
                *(uint2*)&prow[(mb * 16 + quad * 4) ^ swl] = pw;  // wave-private
            }

            // ---- PV: O^T[d][q] += Vt.P; vf straight from L2 ----
            __builtin_amdgcn_s_setprio(1);
#pragma unroll
            for (int ks = 0; ks < 2; ks++) {
                s16x8 pf = *(const s16x8*)&prow[(ks * 32 + quad * 8) ^ swl];
#pragma unroll
                for (int mb = 0; mb < 4; mb++) {
                    s16x8 vf = *(const s16x8*)(kt_v + mb * 1024 + ks * 32);
                    oa[mb].v = __builtin_amdgcn_mfma_f32_16x16x32_bf16(vf, pf, oa[mb].v, 0, 0, 0);
                }
            }
            __builtin_amdgcn_s_setprio(0);
        }

        // ---- lsum reduction across quads (kv partitioned by quad) ----
        lsum += __shfl_xor(lsum, 16, 64);
        lsum += __shfl_xor(lsum, 32, 64);

        // ---- epilogue ----
        float rl = 1.0f / lsum;
        int qrow = qs + wv * 16 + l15;
        float* orow = outg + ((size_t)bh * SQ + qrow) * DH;
#pragma unroll
        for (int mb = 0; mb < 4; mb++) {
            int d0 = mb * 16 + quad * 4;
            *(float4*)(orow + d0) = make_float4(oa[mb].e[0] * rl, oa[mb].e[1] * rl,
                                                oa[mb].e[2] * rl, oa[mb].e[3] * rl);
        }
    }
}

// ---- fallback (no workspace): self-contained, K/V staged through LDS ----
__global__ __launch_bounds__(256, 4)
void attn_fallback(const float* __restrict__ qg, const float* __restrict__ kg,
                   const float* __restrict__ vg, const float* __restrict__ rotg,
                   float* __restrict__ outg)
{
    const int x  = blockIdx.x;
    const int qt = (x & 1) ? (31 - (x >> 1)) : (x >> 1);
    const int bh = blockIdx.y;
    const int bb = bh >> 4, hh = bh & 15;
    const int bkv = bb * 4 + (hh >> 2);
    const int qs = qt * BM;

    const int tid = threadIdx.x;
    const int wv = tid >> 6, lane = tid & 63;
    const int l15 = lane & 15, quad = lane >> 4;
    const int swl = (l15 & 7) << 3;

    __shared__ __align__(16) short QPs[BM * 64];
    __shared__ __align__(16) short Ks[2][BN * 64];
    __shared__ __align__(16) short Vt[2][DH * 64];

    const size_t kvbase = ((size_t)bkv * SQ) * DH;
    const int nkt = (qt / 4 + 1) * 4;
    const int qglob = qs + wv * 16 + l15;

    {   // Q rope inline
        int rr = tid >> 2, c0 = (tid & 3) * 8;
        int srow = qs + rr;
        const float* gq = qg + ((size_t)bh * SQ + srow) * DH;
        float a[8], b[8];
        *(float4*)&a[0] = *(const float4*)(gq + c0);
        *(float4*)&a[4] = *(const float4*)(gq + c0 + 4);
        *(float4*)&b[0] = *(const float4*)(gq + c0 + 32);
        *(float4*)&b[4] = *(const float4*)(gq + c0 + 36);
        U8 o0, o1;
#pragma unroll
        for (int j = 0; j < 8; j++) {
            float2 sc = fsincos(rotg[(size_t)srow * DH + c0 + j]);
            o0.e[j] = (short)f2bf(a[j] * sc.y - b[j] * sc.x);
            o1.e[j] = (short)f2bf(b[j] * sc.y + a[j] * sc.x);
        }
        int sw2 = (rr & 7) << 3;
        *(s16x8*)&QPs[rr * 64 + (c0 ^ sw2)]        = o0.v;
        *(s16x8*)&QPs[rr * 64 + ((c0 + 32) ^ sw2)] = o1.v;
    }
    __syncthreads();

    s16x8 qf[2];
#pragma unroll
    for (int ks = 0; ks < 2; ks++)
        qf[ks] = *(const s16x8*)&QPs[(wv * 16 + l15) * 64 + ((ks * 32 + quad * 8) ^ swl)];

    F4 oa[4];
#pragma unroll
    for (int mb = 0; mb < 4; mb++) oa[mb].v = (f32x4){0.f, 0.f, 0.f, 0.f};
    float lsum = 0.f;

    for (int kt = 0; kt < nkt; kt++) {
        const int cb = kt & 1;
        {   // K rope inline
            int rr = tid >> 2, c0 = (tid & 3) * 8;
            int srow = kt * BN + rr;
            const float* gk = kg + kvbase + (size_t)srow * DH;
            float a[8], b[8];
            *(float4*)&a[0] = *(const float4*)(gk + c0);
            *(float4*)&a[4] = *(const float4*)(gk + c0 + 4);
            *(float4*)&b[0] = *(const float4*)(gk + c0 + 32);
            *(float4*)&b[4] = *(const float4*)(gk + c0 + 36);
            U8 o0, o1;
#pragma unroll
            for (int j = 0; j < 8; j++) {
                float2 sc = fsincos(rotg[(size_t)(srow & (SQ - 1)) * DH + c0 + j]);
                o0.e[j] = (short)f2bf(a[j] * sc.y - b[j] * sc.x);
                o1.e[j] = (short)f2bf(b[j] * sc.y + a[j] * sc.x);
            }
            int sw2 = (rr & 7) << 3;
            *(s16x8*)&Ks[cb][rr * 64 + (c0 ^ sw2)]        = o0.v;
            *(s16x8*)&Ks[cb][rr * 64 + ((c0 + 32) ^ sw2)] = o1.v;
        }
        {   // V transpose inline
            int rr = tid >> 2, c0 = (tid & 3) * 16;
            const float* gv = vg + kvbase + (size_t)(kt * BN + rr) * DH;
            float vv[16];
#pragma unroll
            for (int t = 0; t < 4; t++)
                *(float4*)&vv[t * 4] = *(const float4*)(gv + c0 + t * 4);
#pragma unroll
            for (int j = 0; j < 16; j++) {
                int d = c0 + j;
                Vt[cb][d * 64 + (rr ^ ((d & 7) << 3))] = (short)f2bf(vv[j]);
            }
        }
        __syncthreads();

        F4 sa[4];
#pragma unroll
        for (int mb = 0; mb < 4; mb++) sa[mb].v = (f32x4){0.f, 0.f, 0.f, 0.f};
#pragma unroll
        for (int ks = 0; ks < 2; ks++)
#pragma unroll
            for (int mb = 0; mb < 4; mb++) {
                s16x8 kf = *(const s16x8*)&Ks[cb][(mb * 16 + l15) * 64 + ((ks * 32 + quad * 8) ^ swl)];
                sa[mb].v = __builtin_amdgcn_mfma_f32_16x16x32_bf16(kf, qf[ks], sa[mb].v, 0, 0, 0);
            }

        F4 pa[4];
#pragma unroll
        for (int mb = 0; mb < 4; mb++)
#pragma unroll
            for (int c = 0; c < 4; c++) {
                float t  = sa[mb].e[c] * K1F;
                float w2 = t * t;
                float poly = fmaf(w2, fmaf(w2, KPAF, KPBF), 1.0f);
                pa[mb].e[c] = exp2hw(fmaf(t, poly, -KEF));
            }
        if (kt == 31 && qglob < SPECIAL_START) {
#pragma unroll
            for (int mb = 0; mb < 4; mb++)
#pragma unroll
                for (int c = 0; c < 4; c++) {
                    int kvglob = kt * BN + mb * 16 + quad * 4 + c;
                    if (kvglob >= SPECIAL_START) pa[mb].e[c] = 0.f;
                }
        }
        short* prow = &QPs[(wv * 16 + l15) * 64];
#pragma unroll
        for (int mb = 0; mb < 4; mb++) {
            lsum += (pa[mb].e[0] + pa[mb].e[1]) + (pa[mb].e[2] + pa[mb].e[3]);
            uint2 pw = make_uint2(pkbf(pa[mb].e[0], pa[mb].e[1]),
                                  pkbf(pa[mb].e[2], pa[mb].e[3]));
            *(uint2*)&prow[(mb * 16 + quad * 4) ^ swl] = pw;
        }
#pragma unroll
        for (int ks = 0; ks < 2; ks++) {
            s16x8 pf = *(const s16x8*)&prow[(ks * 32 + quad * 8) ^ swl];
#pragma unroll
            for (int mb = 0; mb < 4; mb++) {
                s16x8 vf = *(const s16x8*)&Vt[cb][(mb * 16 + l15) * 64 + ((ks * 32 + quad * 8) ^ swl)];
                oa[mb].v = __builtin_amdgcn_mfma_f32_16x16x32_bf16(vf, pf, oa[mb].v, 0, 0, 0);
            }
        }
        __syncthreads();
    }

    lsum += __shfl_xor(lsum, 16, 64);
    lsum += __shfl_xor(lsum, 32, 64);

    float rl = 1.0f / lsum;
    int qrow = qs + wv * 16 + l15;
    float* orow = outg + ((size_t)bh * SQ + qrow) * DH;
#pragma unroll
    for (int mb = 0; mb < 4; mb++) {
        int d0 = mb * 16 + quad * 4;
        *(float4*)(orow + d0) = make_float4(oa[mb].e[0] * rl, oa[mb].e[1] * rl,
                                            oa[mb].e[2] * rl, oa[mb].e[3] * rl);
    }
}

extern "C" void kernel_launch(void* const* d_in, const int* in_sizes, int n_in,
                              void* d_out, int out_size, void* d_ws, size_t ws_size,
                              hipStream_t stream) {
    const float* q   = (const float*)d_in[0];
    const float* k   = (const float*)d_in[1];
    const float* v   = (const float*)d_in[2];
    const float* rot = (const float*)d_in[3];
    float* out = (float*)d_out;

    char* w = (char*)d_ws;
    const size_t k_bytes = (size_t)NKV * SQ * DH * sizeof(u16);     // 2 MiB
    const size_t v_bytes = k_bytes;                                 // 2 MiB
    u16* kp = (u16*)w;
    u16* vp = (u16*)(w + k_bytes);
    uint32_t* cnt = (uint32_t*)(w + k_bytes + v_bytes);

    if (ws_size >= k_bytes + v_bytes + sizeof(uint32_t)) {
        hipLaunchKernelGGL(prep_kernel, dim3(VTILES + KBLK), dim3(256), 0, stream,
                           k, v, rot, kp, vp, cnt);
        hipLaunchKernelGGL(attn_fast, dim3(ATTN_GRID), dim3(256), 0, stream,
                           q, rot, kp, vp, cnt, out);
    } else {
        hipLaunchKernelGGL(attn_fallback, dim3(32, NBH), dim3(256), 0, stream,
                           q, k, v, rot, out);
    }
}

// Round 3
// 135.758 us; speedup vs baseline: 1.8399x; 1.8399x over previous
//
#include <hip/hip_runtime.h>
#include <stdint.h>

typedef unsigned short u16;
typedef short s16x8 __attribute__((ext_vector_type(8)));
typedef float f32x4 __attribute__((ext_vector_type(4)));

#define SQ 2048
#define DH 64
#define BM 128             // q rows per block (qt-pair)
#define BN 64              // kv rows per ktile
#define STR 72             // prep-only LDS transpose stride (shorts)
#define SPECIAL_START 2040
#define NBH 32             // b*h
#define NKV 8              // b*hk
#define NQP 16             // qt-pair index 0..15
#define NITEMS (NBH * NQP) // 512 work items (bh, qp)
#define ATTN_GRID 448      // < NITEMS so the queue can rebalance; light 4-ktile tail
// softclamp+softmax folded to exp2: p = 2^( t*poly(t*t) - KEF ), t = s * K1F
#define K1F  0.18033688011112043f    // 0.125 * log2(e)
#define KPAF 4.9244826e-9f           // (2/15)*k^2, k = (0.02/log2e)^2
#define KPBF -6.406040185576019e-5f  // -k/3
#define KEF  36.067376022224085f     // 25 * log2(e)  (constant softmax shift = 25)

union U8 { s16x8 v; short e[8]; };
union F4 { f32x4 v; float e[4]; };

__device__ __forceinline__ u16 f2bf(float x) {  // round-to-nearest-even
    uint32_t u = __float_as_uint(x);
    return (u16)((u + 0x7fffu + ((u >> 16) & 1u)) >> 16);
}
__device__ __forceinline__ uint32_t pkbf(float a, float b) {  // pack 2 bf16, 1 instr
    uint32_t r;
    asm("v_cvt_pk_bf16_f32 %0, %1, %2" : "=v"(r) : "v"(a), "v"(b));
    return r;
}
__device__ __forceinline__ float exp2hw(float x) {
    float r; asm("v_exp_f32 %0, %1" : "=v"(r) : "v"(x)); return r;
}
__device__ __forceinline__ float2 fsincos(float ang) {  // {sin, cos}, fast HW path
    float r = ang * 0.15915494309189535f;   // radians -> revolutions
    r -= floorf(r);
    float s, c;
    asm("v_sin_f32 %0, %1" : "=v"(s) : "v"(r));
    asm("v_cos_f32 %0, %1" : "=v"(c) : "v"(r));
    return make_float2(s, c);
}

// ---- prep: V tiles (transpose to [tile][d][kv]) + K rope rows (bf16) ----
// Q is never prestaged: roped straight into MFMA B-fragments inside attn.
#define VTILES (NKV * 32)                 // 256 tile-blocks
#define RK (NKV * SQ)                     // 16384 K rows
#define KBLK (RK / 32)                    // 512 row-blocks (32 rows each)
__global__ __launch_bounds__(256)
void prep_kernel(const float* __restrict__ kg, const float* __restrict__ vg,
                 const float* __restrict__ rotg,
                 u16* __restrict__ kp, u16* __restrict__ vp,
                 uint32_t* __restrict__ cnt)
{
    const int tid = threadIdx.x;
    if (blockIdx.x == 0 && tid == 0) *cnt = 0u;
    if (blockIdx.x < VTILES) {
        // --- V: one 64x64 tile, transpose through LDS; vp[tile][d][kv] = V[kv][d] ---
        __shared__ short Vls[64 * STR];
        const int tile = blockIdx.x;                   // bkv*32 + kt
        const float* src = vg + ((size_t)(tile >> 5) * SQ + (size_t)(tile & 31) * 64) * DH;
        {
            int kv = tid >> 2, c0 = (tid & 3) * 16;
            const float* s4 = src + (size_t)kv * DH + c0;
            float4 f0 = *(const float4*)(s4);
            float4 f1 = *(const float4*)(s4 + 4);
            float4 f2 = *(const float4*)(s4 + 8);
            float4 f3 = *(const float4*)(s4 + 12);
            uint4 w0 = make_uint4(pkbf(f0.x, f0.y), pkbf(f0.z, f0.w),
                                  pkbf(f1.x, f1.y), pkbf(f1.z, f1.w));
            uint4 w1 = make_uint4(pkbf(f2.x, f2.y), pkbf(f2.z, f2.w),
                                  pkbf(f3.x, f3.y), pkbf(f3.z, f3.w));
            *(uint4*)&Vls[kv * STR + c0]     = w0;
            *(uint4*)&Vls[kv * STR + c0 + 8] = w1;
        }
        __syncthreads();
        {
            int d = tid >> 2, c0 = (tid & 3) * 16;
            U8 o0, o1;
#pragma unroll
            for (int j = 0; j < 16; j++)
                (j < 8 ? o0 : o1).e[j & 7] = Vls[(c0 + j) * STR + d];  // transpose
            u16* dst = vp + (((size_t)tile * 64 + d) << 6) + c0;
            *(s16x8*)dst       = o0.v;
            *(s16x8*)(dst + 8) = o1.v;
        }
    } else {
        // --- K rope: 32 rows per block, 8 elems per thread; HW sin/cos ---
        int bx = blockIdx.x - VTILES;
        int r8 = tid >> 3, c0 = (tid & 7) * 4;      // c0 in 0..28 (<32)
        int r = bx * 32 + r8;                        // r in [0, RK)
        const int s = r & (SQ - 1);
        const float* src = kg + (size_t)r * DH;
        u16*         dst = kp + (size_t)r * DH;
        float4 a  = *(const float4*)(src + c0);
        float4 b  = *(const float4*)(src + c0 + 32);
        float4 rv = *(const float4*)(rotg + (size_t)s * DH + c0);
        float2 s0 = fsincos(rv.x), s1 = fsincos(rv.y),
               s2 = fsincos(rv.z), s3 = fsincos(rv.w);
        float lo0 = a.x * s0.y - b.x * s0.x, hi0 = b.x * s0.y + a.x * s0.x;
        float lo1 = a.y * s1.y - b.y * s1.x, hi1 = b.y * s1.y + a.y * s1.x;
        float lo2 = a.z * s2.y - b.z * s2.x, hi2 = b.z * s2.y + a.z * s2.x;
        float lo3 = a.w * s3.y - b.w * s3.x, hi3 = b.w * s3.y + a.w * s3.x;
        *(uint2*)(dst + c0)      = make_uint2(pkbf(lo0, lo1), pkbf(lo2, lo3));
        *(uint2*)(dst + c0 + 32) = make_uint2(pkbf(hi0, hi1), pkbf(hi2, hi3));
    }
}

// ---- attn: block = 128 q-rows (qt-pair, same nkt for both halves).
// 4 waves; each wave owns 32 q-rows (2 n-tiles) -> each K/V LDS fragment feeds
// 2 MFMAs (operand reuse halves LDS traffic per output). Q roped directly into
// registers (no Q LDS, no Q barrier). K/V: LDS double-buffer + reg prefetch.
// S^T = K.Q^T via mfma(A=K,B=Q)   -> C: col(l15)=q, row(quad*4+c)=kv
// O^T = V^T.P via mfma(A=Vt,B=P)  -> C: col(l15)=q, row(quad*4+c)=d
__global__ __launch_bounds__(256, 3)
void attn_fast(const float* __restrict__ qg, const float* __restrict__ rotg,
               const u16* __restrict__ kp, const u16* __restrict__ vp,
               uint32_t* __restrict__ cnt, float* __restrict__ outg)
{
    const int tid = threadIdx.x;
    const int wv = tid >> 6, lane = tid & 63;
    const int l15 = lane & 15, quad = lane >> 4;
    const int swl = (l15 & 7) << 3;   // fragment-row swizzle (shorts)
    const int r4 = tid >> 2, c16 = (tid & 3) * 16;
    const int swr = (r4 & 7) << 3;    // staging-row swizzle

    __shared__ __align__(16) short Ks[2][BN * 64];   // 16 KB
    __shared__ __align__(16) short Vt[2][DH * 64];   // 16 KB
    __shared__ __align__(16) short Ps[BM * 64];      // 16 KB, wave-private rows
    __shared__ int s_w;

    for (;;) {
        __syncthreads();                       // protect s_w + Ps reuse
        if (tid == 0) s_w = (int)atomicAdd(cnt, 1u);
        __syncthreads();
        const int w = s_w;
        if (w >= NITEMS) break;
        // heavy-first; consecutive pops share bkv for L2 locality
        const int qp = (NQP - 1) - (w >> 5);
        const int u  = w & 31, bkv = u >> 2;
        const int bh = ((bkv >> 2) << 4) | ((bkv & 3) << 2) | (u & 3);
        const int nkt = ((qp >> 1) + 1) << 2;  // block-causal tiles (4..32)
        const int qrow0 = qp * BM + wv * 32;   // this wave's first q row

        // ---- Q rope -> registers. Lane covers cols [quad*8, quad*8+8) and +32,
        // which are exactly the ks=0 / ks=1 B-fragment slices. ----
        s16x8 qf[2][2];
#pragma unroll
        for (int nq = 0; nq < 2; nq++) {
            const int srow = qrow0 + nq * 16 + l15;
            const float* gq = qg + ((size_t)bh * SQ + srow) * DH + quad * 8;
            float a[8], b[8];
            *(float4*)&a[0] = *(const float4*)(gq);
            *(float4*)&a[4] = *(const float4*)(gq + 4);
            *(float4*)&b[0] = *(const float4*)(gq + 32);
            *(float4*)&b[4] = *(const float4*)(gq + 36);
            const float* rrow = rotg + (size_t)srow * DH + quad * 8;
            float lo[8], hi[8];
#pragma unroll
            for (int j = 0; j < 8; j++) {
                float2 sc = fsincos(rrow[j]);
                lo[j] = a[j] * sc.y - b[j] * sc.x;
                hi[j] = b[j] * sc.y + a[j] * sc.x;
            }
            U8 q0, q1;
#pragma unroll
            for (int j = 0; j < 4; j++) {
                ((uint32_t*)&q0.v)[j] = pkbf(lo[2 * j], lo[2 * j + 1]);
                ((uint32_t*)&q1.v)[j] = pkbf(hi[2 * j], hi[2 * j + 1]);
            }
            qf[nq][0] = q0.v;
            qf[nq][1] = q1.v;
        }

        // ---- K/V register prefetch ----
        const u16* kbase = kp + (size_t)bkv * (SQ * DH);
        const u16* vbase = vp + (size_t)bkv * (32 * 64 * 64);
        s16x8 kpr0, kpr1, vpr0, vpr1;
        auto pref = [&](int kt) {
            const u16* srck = kbase + (size_t)(kt * BN + r4) * DH + c16;
            kpr0 = *(const s16x8*)srck;
            kpr1 = *(const s16x8*)(srck + 8);
            const u16* srcv = vbase + ((size_t)kt << 12) + (r4 << 6) + c16;
            vpr0 = *(const s16x8*)srcv;
            vpr1 = *(const s16x8*)(srcv + 8);
        };
        pref(0);

        F4 oa[2][4];
#pragma unroll
        for (int nq = 0; nq < 2; nq++)
#pragma unroll
            for (int mb = 0; mb < 4; mb++) oa[nq][mb].v = (f32x4){0.f, 0.f, 0.f, 0.f};
        float lsum0 = 0.f, lsum1 = 0.f;
        short* prow0 = &Ps[(wv * 32 + l15) * 64];
        short* prow1 = &Ps[(wv * 32 + 16 + l15) * 64];

#pragma unroll 2
        for (int kt = 0; kt < nkt; kt++) {
            const int cb = kt & 1;
            // stage tile kt (other buffer may still be read -> no pre-barrier)
            *(s16x8*)&Ks[cb][r4 * 64 + (c16 ^ swr)]        = kpr0;
            *(s16x8*)&Ks[cb][r4 * 64 + ((c16 + 8) ^ swr)]  = kpr1;
            *(s16x8*)&Vt[cb][r4 * 64 + (c16 ^ swr)]        = vpr0;
            *(s16x8*)&Vt[cb][r4 * 64 + ((c16 + 8) ^ swr)]  = vpr1;
            if (kt + 1 < nkt) pref(kt + 1);   // latency hides under compute
            __syncthreads();

            // ---- QK^T: S^T[kv][q]; each kf feeds both q-tiles ----
            F4 sa[2][4];
            __builtin_amdgcn_s_setprio(1);
#pragma unroll
            for (int ks = 0; ks < 2; ks++)
#pragma unroll
                for (int mb = 0; mb < 4; mb++) {
                    s16x8 kf = *(const s16x8*)&Ks[cb][(mb * 16 + l15) * 64 + ((ks * 32 + quad * 8) ^ swl)];
                    sa[0][mb].v = __builtin_amdgcn_mfma_f32_16x16x32_bf16(
                        kf, qf[0][ks], ks ? sa[0][mb].v : (f32x4){0.f, 0.f, 0.f, 0.f}, 0, 0, 0);
                    sa[1][mb].v = __builtin_amdgcn_mfma_f32_16x16x32_bf16(
                        kf, qf[1][ks], ks ? sa[1][mb].v : (f32x4){0.f, 0.f, 0.f, 0.f}, 0, 0, 0);
                }
            __builtin_amdgcn_s_setprio(0);

            // ---- softclamp + constant-shift softmax (exp2-folded), fused P store ----
            const int last = (kt == 31);
#pragma unroll
            for (int nq = 0; nq < 2; nq++) {
                const int qglob = qrow0 + nq * 16 + l15;
                short* prow = nq ? prow1 : prow0;
                float ls = 0.f;
#pragma unroll
                for (int mb = 0; mb < 4; mb++) {
                    F4 pa;
#pragma unroll
                    for (int c = 0; c < 4; c++) {
                        float t  = sa[nq][mb].e[c] * K1F;
                        float w2 = t * t;
                        float poly = fmaf(w2, fmaf(w2, KPAF, KPBF), 1.0f);
                        pa.e[c] = exp2hw(fmaf(t, poly, -KEF));
                    }
                    if (last && qglob < SPECIAL_START) {   // special-token mask
#pragma unroll
                        for (int c = 0; c < 4; c++) {
                            int kvglob = kt * BN + mb * 16 + quad * 4 + c;
                            if (kvglob >= SPECIAL_START) pa.e[c] = 0.f;
                        }
                    }
                    ls += (pa.e[0] + pa.e[1]) + (pa.e[2] + pa.e[3]);
                    uint2 pw = make_uint2(pkbf(pa.e[0], pa.e[1]),
                                          pkbf(pa.e[2], pa.e[3]));
                    *(uint2*)&prow[(mb * 16 + quad * 4) ^ swl] = pw;  // wave-private
                }
                if (nq) lsum1 += ls; else lsum0 += ls;
            }

            // ---- PV: O^T[d][q] += Vt.P; each vf feeds both q-tiles ----
            __builtin_amdgcn_s_setprio(1);
#pragma unroll
            for (int ks = 0; ks < 2; ks++) {
                s16x8 pf0 = *(const s16x8*)&prow0[(ks * 32 + quad * 8) ^ swl];
                s16x8 pf1 = *(const s16x8*)&prow1[(ks * 32 + quad * 8) ^ swl];
#pragma unroll
                for (int mb = 0; mb < 4; mb++) {
                    s16x8 vf = *(const s16x8*)&Vt[cb][(mb * 16 + l15) * 64 + ((ks * 32 + quad * 8) ^ swl)];
                    oa[0][mb].v = __builtin_amdgcn_mfma_f32_16x16x32_bf16(vf, pf0, oa[0][mb].v, 0, 0, 0);
                    oa[1][mb].v = __builtin_amdgcn_mfma_f32_16x16x32_bf16(vf, pf1, oa[1][mb].v, 0, 0, 0);
                }
            }
            __builtin_amdgcn_s_setprio(0);
        }

        // ---- lsum reduction across quads (kv partitioned by quad) ----
        lsum0 += __shfl_xor(lsum0, 16, 64);
        lsum0 += __shfl_xor(lsum0, 32, 64);
        lsum1 += __shfl_xor(lsum1, 16, 64);
        lsum1 += __shfl_xor(lsum1, 32, 64);

        // ---- epilogue ----
#pragma unroll
        for (int nq = 0; nq < 2; nq++) {
            float rl = 1.0f / (nq ? lsum1 : lsum0);
            int qrow = qrow0 + nq * 16 + l15;
            float* orow = outg + ((size_t)bh * SQ + qrow) * DH;
#pragma unroll
            for (int mb = 0; mb < 4; mb++) {
                int d0 = mb * 16 + quad * 4;
                *(float4*)(orow + d0) = make_float4(oa[nq][mb].e[0] * rl, oa[nq][mb].e[1] * rl,
                                                    oa[nq][mb].e[2] * rl, oa[nq][mb].e[3] * rl);
            }
        }
    }
}

// ---- fallback (no workspace): self-contained, K/V staged through LDS ----
__global__ __launch_bounds__(256, 4)
void attn_fallback(const float* __restrict__ qg, const float* __restrict__ kg,
                   const float* __restrict__ vg, const float* __restrict__ rotg,
                   float* __restrict__ outg)
{
    const int x  = blockIdx.x;
    const int qt = (x & 1) ? (31 - (x >> 1)) : (x >> 1);
    const int bh = blockIdx.y;
    const int bb = bh >> 4, hh = bh & 15;
    const int bkv = bb * 4 + (hh >> 2);
    const int qs = qt * 64;

    const int tid = threadIdx.x;
    const int wv = tid >> 6, lane = tid & 63;
    const int l15 = lane & 15, quad = lane >> 4;
    const int swl = (l15 & 7) << 3;

    __shared__ __align__(16) short QPs[64 * 64];
    __shared__ __align__(16) short Ks[2][BN * 64];
    __shared__ __align__(16) short Vt[2][DH * 64];

    const size_t kvbase = ((size_t)bkv * SQ) * DH;
    const int nkt = (qt / 4 + 1) * 4;
    const int qglob = qs + wv * 16 + l15;

    {   // Q rope inline
        int rr = tid >> 2, c0 = (tid & 3) * 8;
        int srow = qs + rr;
        const float* gq = qg + ((size_t)bh * SQ + srow) * DH;
        float a[8], b[8];
        *(float4*)&a[0] = *(const float4*)(gq + c0);
        *(float4*)&a[4] = *(const float4*)(gq + c0 + 4);
        *(float4*)&b[0] = *(const float4*)(gq + c0 + 32);
        *(float4*)&b[4] = *(const float4*)(gq + c0 + 36);
        U8 o0, o1;
#pragma unroll
        for (int j = 0; j < 8; j++) {
            float2 sc = fsincos(rotg[(size_t)srow * DH + c0 + j]);
            o0.e[j] = (short)f2bf(a[j] * sc.y - b[j] * sc.x);
            o1.e[j] = (short)f2bf(b[j] * sc.y + a[j] * sc.x);
        }
        int sw2 = (rr & 7) << 3;
        *(s16x8*)&QPs[rr * 64 + (c0 ^ sw2)]        = o0.v;
        *(s16x8*)&QPs[rr * 64 + ((c0 + 32) ^ sw2)] = o1.v;
    }
    __syncthreads();

    s16x8 qf[2];
#pragma unroll
    for (int ks = 0; ks < 2; ks++)
        qf[ks] = *(const s16x8*)&QPs[(wv * 16 + l15) * 64 + ((ks * 32 + quad * 8) ^ swl)];

    F4 oa[4];
#pragma unroll
    for (int mb = 0; mb < 4; mb++) oa[mb].v = (f32x4){0.f, 0.f, 0.f, 0.f};
    float lsum = 0.f;

    for (int kt = 0; kt < nkt; kt++) {
        const int cb = kt & 1;
        {   // K rope inline
            int rr = tid >> 2, c0 = (tid & 3) * 8;
            int srow = kt * BN + rr;
            const float* gk = kg + kvbase + (size_t)srow * DH;
            float a[8], b[8];
            *(float4*)&a[0] = *(const float4*)(gk + c0);
            *(float4*)&a[4] = *(const float4*)(gk + c0 + 4);
            *(float4*)&b[0] = *(const float4*)(gk + c0 + 32);
            *(float4*)&b[4] = *(const float4*)(gk + c0 + 36);
            U8 o0, o1;
#pragma unroll
            for (int j = 0; j < 8; j++) {
                float2 sc = fsincos(rotg[(size_t)(srow & (SQ - 1)) * DH + c0 + j]);
                o0.e[j] = (short)f2bf(a[j] * sc.y - b[j] * sc.x);
                o1.e[j] = (short)f2bf(b[j] * sc.y + a[j] * sc.x);
            }
            int sw2 = (rr & 7) << 3;
            *(s16x8*)&Ks[cb][rr * 64 + (c0 ^ sw2)]        = o0.v;
            *(s16x8*)&Ks[cb][rr * 64 + ((c0 + 32) ^ sw2)] = o1.v;
        }
        {   // V transpose inline
            int rr = tid >> 2, c0 = (tid & 3) * 16;
            const float* gv = vg + kvbase + (size_t)(kt * BN + rr) * DH;
            float vv[16];
#pragma unroll
            for (int t = 0; t < 4; t++)
                *(float4*)&vv[t * 4] = *(const float4*)(gv + c0 + t * 4);
#pragma unroll
            for (int j = 0; j < 16; j++) {
                int d = c0 + j;
                Vt[cb][d * 64 + (rr ^ ((d & 7) << 3))] = (short)f2bf(vv[j]);
            }
        }
        __syncthreads();

        F4 sa[4];
#pragma unroll
        for (int mb = 0; mb < 4; mb++) sa[mb].v = (f32x4){0.f, 0.f, 0.f, 0.f};
#pragma unroll
        for (int ks = 0; ks < 2; ks++)
#pragma unroll
            for (int mb = 0; mb < 4; mb++) {
                s16x8 kf = *(const s16x8*)&Ks[cb][(mb * 16 + l15) * 64 + ((ks * 32 + quad * 8) ^ swl)];
                sa[mb].v = __builtin_amdgcn_mfma_f32_16x16x32_bf16(kf, qf[ks], sa[mb].v, 0, 0, 0);
            }

        F4 pa[4];
#pragma unroll
        for (int mb = 0; mb < 4; mb++)
#pragma unroll
            for (int c = 0; c < 4; c++) {
                float t  = sa[mb].e[c] * K1F;
                float w2 = t * t;
                float poly = fmaf(w2, fmaf(w2, KPAF, KPBF), 1.0f);
                pa[mb].e[c] = exp2hw(fmaf(t, poly, -KEF));
            }
        if (kt == 31 && qglob < SPECIAL_START) {
#pragma unroll
            for (int mb = 0; mb < 4; mb++)
#pragma unroll
                for (int c = 0; c < 4; c++) {
                    int kvglob = kt * BN + mb * 16 + quad * 4 + c;
                    if (kvglob >= SPECIAL_START) pa[mb].e[c] = 0.f;
                }
        }
        short* prow = &QPs[(wv * 16 + l15) * 64];
#pragma unroll
        for (int mb = 0; mb < 4; mb++) {
            lsum += (pa[mb].e[0] + pa[mb].e[1]) + (pa[mb].e[2] + pa[mb].e[3]);
            uint2 pw = make_uint2(pkbf(pa[mb].e[0], pa[mb].e[1]),
                                  pkbf(pa[mb].e[2], pa[mb].e[3]));
            *(uint2*)&prow[(mb * 16 + quad * 4) ^ swl] = pw;
        }
#pragma unroll
        for (int ks = 0; ks < 2; ks++) {
            s16x8 pf = *(const s16x8*)&prow[(ks * 32 + quad * 8) ^ swl];
#pragma unroll
            for (int mb = 0; mb < 4; mb++) {
                s16x8 vf = *(const s16x8*)&Vt[cb][(mb * 16 + l15) * 64 + ((ks * 32 + quad * 8) ^ swl)];
                oa[mb].v = __builtin_amdgcn_mfma_f32_16x16x32_bf16(vf, pf, oa[mb].v, 0, 0, 0);
            }
        }
        __syncthreads();
    }

    lsum += __shfl_xor(lsum, 16, 64);
    lsum += __shfl_xor(lsum, 32, 64);

    float rl = 1.0f / lsum;
    int qrow = qs + wv * 16 + l15;
    float* orow = outg + ((size_t)bh * SQ + qrow) * DH;
#pragma unroll
    for (int mb = 0; mb < 4; mb++) {
        int d0 = mb * 16 + quad * 4;
        *(float4*)(orow + d0) = make_float4(oa[mb].e[0] * rl, oa[mb].e[1] * rl,
                                            oa[mb].e[2] * rl, oa[mb].e[3] * rl);
    }
}

extern "C" void kernel_launch(void* const* d_in, const int* in_sizes, int n_in,
                              void* d_out, int out_size, void* d_ws, size_t ws_size,
                              hipStream_t stream) {
    const float* q   = (const float*)d_in[0];
    const float* k   = (const float*)d_in[1];
    const float* v   = (const float*)d_in[2];
    const float* rot = (const float*)d_in[3];
    float* out = (float*)d_out;

    char* w = (char*)d_ws;
    const size_t k_bytes = (size_t)NKV * SQ * DH * sizeof(u16);     // 2 MiB
    const size_t v_bytes = k_bytes;                                 // 2 MiB
    u16* kp = (u16*)w;
    u16* vp = (u16*)(w + k_bytes);
    uint32_t* cnt = (uint32_t*)(w + k_bytes + v_bytes);

    if (ws_size >= k_bytes + v_bytes + sizeof(uint32_t)) {
        hipLaunchKernelGGL(prep_kernel, dim3(VTILES + KBLK), dim3(256), 0, stream,
                           k, v, rot, kp, vp, cnt);
        hipLaunchKernelGGL(attn_fast, dim3(ATTN_GRID), dim3(256), 0, stream,
                           q, rot, kp, vp, cnt, out);
    } else {
        hipLaunchKernelGGL(attn_fallback, dim3(32, NBH), dim3(256), 0, stream,
                           q, k, v, rot, out);
    }
}

// Round 4
// 135.666 us; speedup vs baseline: 1.8412x; 1.0007x over previous
//
#include <hip/hip_runtime.h>
#include <stdint.h>

typedef unsigned short u16;
typedef short s16x8 __attribute__((ext_vector_type(8)));
typedef float f32x4 __attribute__((ext_vector_type(4)));

#define SQ 2048
#define DH 64
#define BM 128             // q rows per block (qt-pair)
#define BN 64              // kv rows per ktile
#define STR 72             // prep-only LDS transpose stride (shorts)
#define SPECIAL_START 2040
#define NBH 32             // b*h
#define NKV 8              // b*hk
#define NQP 16             // qt-pair index 0..15
#define NITEMS (NBH * NQP) // 512 work items (bh, qp)
#define ATTN_GRID 480      // 2 blocks/CU x 240 CUs; queue feeds the light tail
// softclamp+softmax folded to exp2: p = 2^( t*poly(t*t) - KEF ), t = s * K1F
#define K1F  0.18033688011112043f    // 0.125 * log2(e)
#define KPAF 4.9244826e-9f           // (2/15)*k^2, k = (0.02/log2e)^2
#define KPBF -6.406040185576019e-5f  // -k/3
#define KEF  36.067376022224085f     // 25 * log2(e)  (constant softmax shift = 25)

union U8 { s16x8 v; short e[8]; };
union F4 { f32x4 v; float e[4]; };

__device__ __forceinline__ u16 f2bf(float x) {  // round-to-nearest-even
    uint32_t u = __float_as_uint(x);
    return (u16)((u + 0x7fffu + ((u >> 16) & 1u)) >> 16);
}
__device__ __forceinline__ uint32_t pkbf(float a, float b) {  // pack 2 bf16, 1 instr
    uint32_t r;
    asm("v_cvt_pk_bf16_f32 %0, %1, %2" : "=v"(r) : "v"(a), "v"(b));
    return r;
}
__device__ __forceinline__ float exp2hw(float x) {
    float r; asm("v_exp_f32 %0, %1" : "=v"(r) : "v"(x)); return r;
}
__device__ __forceinline__ float2 fsincos(float ang) {  // {sin, cos}, fast HW path
    float r = ang * 0.15915494309189535f;   // radians -> revolutions
    r -= floorf(r);
    float s, c;
    asm("v_sin_f32 %0, %1" : "=v"(s) : "v"(r));
    asm("v_cos_f32 %0, %1" : "=v"(c) : "v"(r));
    return make_float2(s, c);
}

// ---- prep: V tiles (transpose to [tile][d][kv]) + K rope rows (bf16) ----
#define VTILES (NKV * 32)                 // 256 tile-blocks
#define RK (NKV * SQ)                     // 16384 K rows
#define KBLK (RK / 32)                    // 512 row-blocks (32 rows each)
__global__ __launch_bounds__(256)
void prep_kernel(const float* __restrict__ kg, const float* __restrict__ vg,
                 const float* __restrict__ rotg,
                 u16* __restrict__ kp, u16* __restrict__ vp,
                 uint32_t* __restrict__ cnt)
{
    const int tid = threadIdx.x;
    if (blockIdx.x == 0 && tid == 0) *cnt = 0u;
    if (blockIdx.x < VTILES) {
        __shared__ short Vls[64 * STR];
        const int tile = blockIdx.x;                   // bkv*32 + kt
        const float* src = vg + ((size_t)(tile >> 5) * SQ + (size_t)(tile & 31) * 64) * DH;
        {
            int kv = tid >> 2, c0 = (tid & 3) * 16;
            const float* s4 = src + (size_t)kv * DH + c0;
            float4 f0 = *(const float4*)(s4);
            float4 f1 = *(const float4*)(s4 + 4);
            float4 f2 = *(const float4*)(s4 + 8);
            float4 f3 = *(const float4*)(s4 + 12);
            uint4 w0 = make_uint4(pkbf(f0.x, f0.y), pkbf(f0.z, f0.w),
                                  pkbf(f1.x, f1.y), pkbf(f1.z, f1.w));
            uint4 w1 = make_uint4(pkbf(f2.x, f2.y), pkbf(f2.z, f2.w),
                                  pkbf(f3.x, f3.y), pkbf(f3.z, f3.w));
            *(uint4*)&Vls[kv * STR + c0]     = w0;
            *(uint4*)&Vls[kv * STR + c0 + 8] = w1;
        }
        __syncthreads();
        {
            int d = tid >> 2, c0 = (tid & 3) * 16;
            U8 o0, o1;
#pragma unroll
            for (int j = 0; j < 16; j++)
                (j < 8 ? o0 : o1).e[j & 7] = Vls[(c0 + j) * STR + d];  // transpose
            u16* dst = vp + (((size_t)tile * 64 + d) << 6) + c0;
            *(s16x8*)dst       = o0.v;
            *(s16x8*)(dst + 8) = o1.v;
        }
    } else {
        int bx = blockIdx.x - VTILES;
        int r8 = tid >> 3, c0 = (tid & 7) * 4;      // c0 in 0..28 (<32)
        int r = bx * 32 + r8;                        // r in [0, RK)
        const int s = r & (SQ - 1);
        const float* src = kg + (size_t)r * DH;
        u16*         dst = kp + (size_t)r * DH;
        float4 a  = *(const float4*)(src + c0);
        float4 b  = *(const float4*)(src + c0 + 32);
        float4 rv = *(const float4*)(rotg + (size_t)s * DH + c0);
        float2 s0 = fsincos(rv.x), s1 = fsincos(rv.y),
               s2 = fsincos(rv.z), s3 = fsincos(rv.w);
        float lo0 = a.x * s0.y - b.x * s0.x, hi0 = b.x * s0.y + a.x * s0.x;
        float lo1 = a.y * s1.y - b.y * s1.x, hi1 = b.y * s1.y + a.y * s1.x;
        float lo2 = a.z * s2.y - b.z * s2.x, hi2 = b.z * s2.y + a.z * s2.x;
        float lo3 = a.w * s3.y - b.w * s3.x, hi3 = b.w * s3.y + a.w * s3.x;
        *(uint2*)(dst + c0)      = make_uint2(pkbf(lo0, lo1), pkbf(lo2, lo3));
        *(uint2*)(dst + c0 + 32) = make_uint2(pkbf(hi0, hi1), pkbf(hi2, hi3));
    }
}

// ---- attn: 8 waves / 512 threads. Waves 0-3 ("group A") process K-tiles
// [0, nkt/2); waves 4-7 ("group B") process [nkt/2, nkt) of the SAME 128
// q-rows. nkt is a multiple of 4 -> halves are exactly equal -> uniform
// barriers. Constant-shift softmax => combine is just O~A+O~B and lA+lB.
// Each wave: 32 q-rows, K/V fragments shared across its 2 q-tiles.
// K/V single-buffered per group (dbuf traded for 2 blocks/CU residency).
// S^T = K.Q^T via mfma(A=K,B=Q)   -> C: col(l15)=q, row(quad*4+c)=kv
// O^T = V^T.P via mfma(A=Vt,B=P)  -> C: col(l15)=q, row(quad*4+c)=d
__global__ __launch_bounds__(512, 4)
void attn_fast(const float* __restrict__ qg, const float* __restrict__ rotg,
               const u16* __restrict__ kp, const u16* __restrict__ vp,
               uint32_t* __restrict__ cnt, float* __restrict__ outg)
{
    const int tid = threadIdx.x;
    const int wv = tid >> 6, lane = tid & 63;
    const int l15 = lane & 15, quad = lane >> 4;
    const int grp = wv >> 2, wl = wv & 3;     // half-group, wave-in-group
    const int tl = tid & 255;                  // thread-in-group
    const int r4 = tl >> 2, c16 = (tl & 3) * 16;
    const int swr = (r4 & 7) << 3;             // staging-row swizzle
    const int swl = (l15 & 7) << 3;            // fragment-row swizzle

    // shorts: [0,8192) K halves | [8192,16384) V halves | [16384,32768) P
    __shared__ __align__(16) short SM[32768];  // 64 KB
    __shared__ int s_w;
    short* Ksg  = SM + grp * 4096;
    short* Vtg  = SM + 8192 + grp * 4096;
    short* Psg  = SM + 16384 + grp * 8192;
    float* comb  = (float*)SM;                 // 8192 f32 = K+V region (post-loop)
    float* lsumB = (float*)(SM + 16384);       // 128 f32 in P region (post-loop)

    for (;;) {
        __syncthreads();                       // protect s_w + comb/P reuse
        if (tid == 0) s_w = (int)atomicAdd(cnt, 1u);
        __syncthreads();
        const int w = s_w;
        if (w >= NITEMS) break;
        const int qp = (NQP - 1) - (w >> 5);   // heavy-first
        const int u  = w & 31, bkv = u >> 2;   // consecutive pops share bkv
        const int bh = ((bkv >> 2) << 4) | ((bkv & 3) << 2) | (u & 3);
        const int nkt = ((qp >> 1) + 1) << 2;  // 4..32, multiple of 4
        const int h   = nkt >> 1;              // this group's tile count
        const int kt0 = grp ? h : 0;
        const int qrow0 = qp * BM + wl * 32;

        // ---- K/V register prefetch (issued FIRST: L2 latency hides under rope) ----
        const u16* kbase = kp + (size_t)bkv * (SQ * DH);
        const u16* vbase = vp + (size_t)bkv * (32 * 64 * 64);
        s16x8 kpr0, kpr1, vpr0, vpr1;
        auto pref = [&](int kt) {
            const u16* srck = kbase + (size_t)(kt * BN + r4) * DH + c16;
            kpr0 = *(const s16x8*)srck;
            kpr1 = *(const s16x8*)(srck + 8);
            const u16* srcv = vbase + ((size_t)kt << 12) + (r4 << 6) + c16;
            vpr0 = *(const s16x8*)srcv;
            vpr1 = *(const s16x8*)(srcv + 8);
        };
        pref(kt0);

        // ---- Q rope -> registers (both groups rope the same q rows) ----
        s16x8 qf[2][2];
#pragma unroll
        for (int nq = 0; nq < 2; nq++) {
            const int srow = qrow0 + nq * 16 + l15;
            const float* gq = qg + ((size_t)bh * SQ + srow) * DH + quad * 8;
            float a[8], b[8];
            *(float4*)&a[0] = *(const float4*)(gq);
            *(float4*)&a[4] = *(const float4*)(gq + 4);
            *(float4*)&b[0] = *(const float4*)(gq + 32);
            *(float4*)&b[4] = *(const float4*)(gq + 36);
            const float* rrow = rotg + (size_t)srow * DH + quad * 8;
            float lo[8], hi[8];
#pragma unroll
            for (int j = 0; j < 8; j++) {
                float2 sc = fsincos(rrow[j]);
                lo[j] = a[j] * sc.y - b[j] * sc.x;
                hi[j] = b[j] * sc.y + a[j] * sc.x;
            }
            U8 q0, q1;
#pragma unroll
            for (int j = 0; j < 4; j++) {
                ((uint32_t*)&q0.v)[j] = pkbf(lo[2 * j], lo[2 * j + 1]);
                ((uint32_t*)&q1.v)[j] = pkbf(hi[2 * j], hi[2 * j + 1]);
            }
            qf[nq][0] = q0.v;
            qf[nq][1] = q1.v;
        }

        F4 oa[2][4];
#pragma unroll
        for (int nq = 0; nq < 2; nq++)
#pragma unroll
            for (int mb = 0; mb < 4; mb++) oa[nq][mb].v = (f32x4){0.f, 0.f, 0.f, 0.f};
        float lsum0 = 0.f, lsum1 = 0.f;
        short* prow0 = &Psg[(wl * 32 + l15) * 64];
        short* prow1 = &Psg[(wl * 32 + 16 + l15) * 64];

        for (int i = 0; i < h; i++) {
            const int kt = kt0 + i;
            // stage this group's tile (single buffer; prev compute done at
            // end-of-iter barrier, prefetch regs carry the data)
            *(s16x8*)&Ksg[r4 * 64 + (c16 ^ swr)]       = kpr0;
            *(s16x8*)&Ksg[r4 * 64 + ((c16 + 8) ^ swr)] = kpr1;
            *(s16x8*)&Vtg[r4 * 64 + (c16 ^ swr)]       = vpr0;
            *(s16x8*)&Vtg[r4 * 64 + ((c16 + 8) ^ swr)] = vpr1;
            if (i + 1 < h) pref(kt + 1);   // next-tile loads fly under compute
            __syncthreads();

            // ---- QK^T: S^T[kv][q]; each kf feeds both q-tiles ----
            F4 sa[2][4];
            __builtin_amdgcn_s_setprio(1);
#pragma unroll
            for (int ks = 0; ks < 2; ks++)
#pragma unroll
                for (int mb = 0; mb < 4; mb++) {
                    s16x8 kf = *(const s16x8*)&Ksg[(mb * 16 + l15) * 64 + ((ks * 32 + quad * 8) ^ swl)];
                    sa[0][mb].v = __builtin_amdgcn_mfma_f32_16x16x32_bf16(
                        kf, qf[0][ks], ks ? sa[0][mb].v : (f32x4){0.f, 0.f, 0.f, 0.f}, 0, 0, 0);
                    sa[1][mb].v = __builtin_amdgcn_mfma_f32_16x16x32_bf16(
                        kf, qf[1][ks], ks ? sa[1][mb].v : (f32x4){0.f, 0.f, 0.f, 0.f}, 0, 0, 0);
                }
            __builtin_amdgcn_s_setprio(0);

            // ---- softclamp + constant-shift softmax (exp2-folded) + P store ----
            const int last = (kt == 31);
#pragma unroll
            for (int nq = 0; nq < 2; nq++) {
                const int qglob = qrow0 + nq * 16 + l15;
                short* prow = nq ? prow1 : prow0;
                float ls = 0.f;
#pragma unroll
                for (int mb = 0; mb < 4; mb++) {
                    F4 pa;
#pragma unroll
                    for (int c = 0; c < 4; c++) {
                        float t  = sa[nq][mb].e[c] * K1F;
                        float w2 = t * t;
                        float poly = fmaf(w2, fmaf(w2, KPAF, KPBF), 1.0f);
                        pa.e[c] = exp2hw(fmaf(t, poly, -KEF));
                    }
                    if (last && qglob < SPECIAL_START) {   // special-token mask
#pragma unroll
                        for (int c = 0; c < 4; c++) {
                            int kvglob = kt * BN + mb * 16 + quad * 4 + c;
                            if (kvglob >= SPECIAL_START) pa.e[c] = 0.f;
                        }
                    }
                    ls += (pa.e[0] + pa.e[1]) + (pa.e[2] + pa.e[3]);
                    uint2 pw = make_uint2(pkbf(pa.e[0], pa.e[1]),
                                          pkbf(pa.e[2], pa.e[3]));
                    *(uint2*)&prow[(mb * 16 + quad * 4) ^ swl] = pw;  // wave-private
                }
                if (nq) lsum1 += ls; else lsum0 += ls;
            }

            // ---- PV: O^T[d][q] += Vt.P; each vf feeds both q-tiles ----
            __builtin_amdgcn_s_setprio(1);
#pragma unroll
            for (int ks = 0; ks < 2; ks++) {
                s16x8 pf0 = *(const s16x8*)&prow0[(ks * 32 + quad * 8) ^ swl];
                s16x8 pf1 = *(const s16x8*)&prow1[(ks * 32 + quad * 8) ^ swl];
#pragma unroll
                for (int mb = 0; mb < 4; mb++) {
                    s16x8 vf = *(const s16x8*)&Vtg[(mb * 16 + l15) * 64 + ((ks * 32 + quad * 8) ^ swl)];
                    oa[0][mb].v = __builtin_amdgcn_mfma_f32_16x16x32_bf16(vf, pf0, oa[0][mb].v, 0, 0, 0);
                    oa[1][mb].v = __builtin_amdgcn_mfma_f32_16x16x32_bf16(vf, pf1, oa[1][mb].v, 0, 0, 0);
                }
            }
            __builtin_amdgcn_s_setprio(0);
            __syncthreads();   // compute done: group may overwrite Ks/Vt next iter
        }

        // ---- per-half lsum reduction across quads (kv partitioned by quad) ----
        lsum0 += __shfl_xor(lsum0, 16, 64);
        lsum0 += __shfl_xor(lsum0, 32, 64);
        lsum1 += __shfl_xor(lsum1, 16, 64);
        lsum1 += __shfl_xor(lsum1, 32, 64);

        // ---- combine halves: B drops O~ + lsum into LDS, A adds + normalizes ----
        if (grp) {
#pragma unroll
            for (int nq = 0; nq < 2; nq++) {
                const int row = wl * 32 + nq * 16 + l15;
#pragma unroll
                for (int mb = 0; mb < 4; mb++)
                    *(float4*)&comb[row * 64 + mb * 16 + quad * 4] =
                        make_float4(oa[nq][mb].e[0], oa[nq][mb].e[1],
                                    oa[nq][mb].e[2], oa[nq][mb].e[3]);
                if (quad == 0) lsumB[row] = nq ? lsum1 : lsum0;
            }
        }
        __syncthreads();
        if (!grp) {
#pragma unroll
            for (int nq = 0; nq < 2; nq++) {
                const int row = wl * 32 + nq * 16 + l15;
                const float rl = 1.0f / ((nq ? lsum1 : lsum0) + lsumB[row]);
                float* orow = outg + ((size_t)bh * SQ + qp * BM + row) * DH;
#pragma unroll
                for (int mb = 0; mb < 4; mb++) {
                    const int d0 = mb * 16 + quad * 4;
                    float4 cb = *(float4*)&comb[row * 64 + d0];
                    *(float4*)(orow + d0) = make_float4((oa[nq][mb].e[0] + cb.x) * rl,
                                                        (oa[nq][mb].e[1] + cb.y) * rl,
                                                        (oa[nq][mb].e[2] + cb.z) * rl,
                                                        (oa[nq][mb].e[3] + cb.w) * rl);
                }
            }
        }
    }
}

// ---- fallback (no workspace): self-contained, K/V staged through LDS ----
__global__ __launch_bounds__(256, 4)
void attn_fallback(const float* __restrict__ qg, const float* __restrict__ kg,
                   const float* __restrict__ vg, const float* __restrict__ rotg,
                   float* __restrict__ outg)
{
    const int x  = blockIdx.x;
    const int qt = (x & 1) ? (31 - (x >> 1)) : (x >> 1);
    const int bh = blockIdx.y;
    const int bb = bh >> 4, hh = bh & 15;
    const int bkv = bb * 4 + (hh >> 2);
    const int qs = qt * 64;

    const int tid = threadIdx.x;
    const int wv = tid >> 6, lane = tid & 63;
    const int l15 = lane & 15, quad = lane >> 4;
    const int swl = (l15 & 7) << 3;

    __shared__ __align__(16) short QPs[64 * 64];
    __shared__ __align__(16) short Ks[2][BN * 64];
    __shared__ __align__(16) short Vt[2][DH * 64];

    const size_t kvbase = ((size_t)bkv * SQ) * DH;
    const int nkt = (qt / 4 + 1) * 4;
    const int qglob = qs + wv * 16 + l15;

    {   // Q rope inline
        int rr = tid >> 2, c0 = (tid & 3) * 8;
        int srow = qs + rr;
        const float* gq = qg + ((size_t)bh * SQ + srow) * DH;
        float a[8], b[8];
        *(float4*)&a[0] = *(const float4*)(gq + c0);
        *(float4*)&a[4] = *(const float4*)(gq + c0 + 4);
        *(float4*)&b[0] = *(const float4*)(gq + c0 + 32);
        *(float4*)&b[4] = *(const float4*)(gq + c0 + 36);
        U8 o0, o1;
#pragma unroll
        for (int j = 0; j < 8; j++) {
            float2 sc = fsincos(rotg[(size_t)srow * DH + c0 + j]);
            o0.e[j] = (short)f2bf(a[j] * sc.y - b[j] * sc.x);
            o1.e[j] = (short)f2bf(b[j] * sc.y + a[j] * sc.x);
        }
        int sw2 = (rr & 7) << 3;
        *(s16x8*)&QPs[rr * 64 + (c0 ^ sw2)]        = o0.v;
        *(s16x8*)&QPs[rr * 64 + ((c0 + 32) ^ sw2)] = o1.v;
    }
    __syncthreads();

    s16x8 qf[2];
#pragma unroll
    for (int ks = 0; ks < 2; ks++)
        qf[ks] = *(const s16x8*)&QPs[(wv * 16 + l15) * 64 + ((ks * 32 + quad * 8) ^ swl)];

    F4 oa[4];
#pragma unroll
    for (int mb = 0; mb < 4; mb++) oa[mb].v = (f32x4){0.f, 0.f, 0.f, 0.f};
    float lsum = 0.f;

    for (int kt = 0; kt < nkt; kt++) {
        const int cb = kt & 1;
        {   // K rope inline
            int rr = tid >> 2, c0 = (tid & 3) * 8;
            int srow = kt * BN + rr;
            const float* gk = kg + kvbase + (size_t)srow * DH;
            float a[8], b[8];
            *(float4*)&a[0] = *(const float4*)(gk + c0);
            *(float4*)&a[4] = *(const float4*)(gk + c0 + 4);
            *(float4*)&b[0] = *(const float4*)(gk + c0 + 32);
            *(float4*)&b[4] = *(const float4*)(gk + c0 + 36);
            U8 o0, o1;
#pragma unroll
            for (int j = 0; j < 8; j++) {
                float2 sc = fsincos(rotg[(size_t)(srow & (SQ - 1)) * DH + c0 + j]);
                o0.e[j] = (short)f2bf(a[j] * sc.y - b[j] * sc.x);
                o1.e[j] = (short)f2bf(b[j] * sc.y + a[j] * sc.x);
            }
            int sw2 = (rr & 7) << 3;
            *(s16x8*)&Ks[cb][rr * 64 + (c0 ^ sw2)]        = o0.v;
            *(s16x8*)&Ks[cb][rr * 64 + ((c0 + 32) ^ sw2)] = o1.v;
        }
        {   // V transpose inline
            int rr = tid >> 2, c0 = (tid & 3) * 16;
            const float* gv = vg + kvbase + (size_t)(kt * BN + rr) * DH;
            float vv[16];
#pragma unroll
            for (int t = 0; t < 4; t++)
                *(float4*)&vv[t * 4] = *(const float4*)(gv + c0 + t * 4);
#pragma unroll
            for (int j = 0; j < 16; j++) {
                int d = c0 + j;
                Vt[cb][d * 64 + (rr ^ ((d & 7) << 3))] = (short)f2bf(vv[j]);
            }
        }
        __syncthreads();

        F4 sa[4];
#pragma unroll
        for (int mb = 0; mb < 4; mb++) sa[mb].v = (f32x4){0.f, 0.f, 0.f, 0.f};
#pragma unroll
        for (int ks = 0; ks < 2; ks++)
#pragma unroll
            for (int mb = 0; mb < 4; mb++) {
                s16x8 kf = *(const s16x8*)&Ks[cb][(mb * 16 + l15) * 64 + ((ks * 32 + quad * 8) ^ swl)];
                sa[mb].v = __builtin_amdgcn_mfma_f32_16x16x32_bf16(kf, qf[ks], sa[mb].v, 0, 0, 0);
            }

        F4 pa[4];
#pragma unroll
        for (int mb = 0; mb < 4; mb++)
#pragma unroll
            for (int c = 0; c < 4; c++) {
                float t  = sa[mb].e[c] * K1F;
                float w2 = t * t;
                float poly = fmaf(w2, fmaf(w2, KPAF, KPBF), 1.0f);
                pa[mb].e[c] = exp2hw(fmaf(t, poly, -KEF));
            }
        if (kt == 31 && qglob < SPECIAL_START) {
#pragma unroll
            for (int mb = 0; mb < 4; mb++)
#pragma unroll
                for (int c = 0; c < 4; c++) {
                    int kvglob = kt * BN + mb * 16 + quad * 4 + c;
                    if (kvglob >= SPECIAL_START) pa[mb].e[c] = 0.f;
                }
        }
        short* prow = &QPs[(wv * 16 + l15) * 64];
#pragma unroll
        for (int mb = 0; mb < 4; mb++) {
            lsum += (pa[mb].e[0] + pa[mb].e[1]) + (pa[mb].e[2] + pa[mb].e[3]);
            uint2 pw = make_uint2(pkbf(pa[mb].e[0], pa[mb].e[1]),
                                  pkbf(pa[mb].e[2], pa[mb].e[3]));
            *(uint2*)&prow[(mb * 16 + quad * 4) ^ swl] = pw;
        }
#pragma unroll
        for (int ks = 0; ks < 2; ks++) {
            s16x8 pf = *(const s16x8*)&prow[(ks * 32 + quad * 8) ^ swl];
#pragma unroll
            for (int mb = 0; mb < 4; mb++) {
                s16x8 vf = *(const s16x8*)&Vt[cb][(mb * 16 + l15) * 64 + ((ks * 32 + quad * 8) ^ swl)];
                oa[mb].v = __builtin_amdgcn_mfma_f32_16x16x32_bf16(vf, pf, oa[mb].v, 0, 0, 0);
            }
        }
        __syncthreads();
    }

    lsum += __shfl_xor(lsum, 16, 64);
    lsum += __shfl_xor(lsum, 32, 64);

    float rl = 1.0f / lsum;
    int qrow = qs + wv * 16 + l15;
    float* orow = outg + ((size_t)bh * SQ + qrow) * DH;
#pragma unroll
    for (int mb = 0; mb < 4; mb++) {
        int d0 = mb * 16 + quad * 4;
        *(float4*)(orow + d0) = make_float4(oa[mb].e[0] * rl, oa[mb].e[1] * rl,
                                            oa[mb].e[2] * rl, oa[mb].e[3] * rl);
    }
}

extern "C" void kernel_launch(void* const* d_in, const int* in_sizes, int n_in,
                              void* d_out, int out_size, void* d_ws, size_t ws_size,
                              hipStream_t stream) {
    const float* q   = (const float*)d_in[0];
    const float* k   = (const float*)d_in[1];
    const float* v   = (const float*)d_in[2];
    const float* rot = (const float*)d_in[3];
    float* out = (float*)d_out;

    char* w = (char*)d_ws;
    const size_t k_bytes = (size_t)NKV * SQ * DH * sizeof(u16);     // 2 MiB
    const size_t v_bytes = k_bytes;                                 // 2 MiB
    u16* kp = (u16*)w;
    u16* vp = (u16*)(w + k_bytes);
    uint32_t* cnt = (uint32_t*)(w + k_bytes + v_bytes);

    if (ws_size >= k_bytes + v_bytes + sizeof(uint32_t)) {
        hipLaunchKernelGGL(prep_kernel, dim3(VTILES + KBLK), dim3(256), 0, stream,
                           k, v, rot, kp, vp, cnt);
        hipLaunchKernelGGL(attn_fast, dim3(ATTN_GRID), dim3(512), 0, stream,
                           q, rot, kp, vp, cnt, out);
    } else {
        hipLaunchKernelGGL(attn_fallback, dim3(32, NBH), dim3(256), 0, stream,
                           q, k, v, rot, out);
    }
}